// Round 3
// baseline (507.770 us; speedup 1.0000x reference)
//
#include <hip/hip_runtime.h>
#include <hip/hip_bf16.h>
#include <stdint.h>

// Problem constants
#define N_ROWS 65536
#define DIM 1024
#define SDIM 200
#define SCORE_COLS 81
#define BBOX_COLS 324
#define GEMM_COLS 384      // 1 (cls) + 12 (folded sem->cls) + 324 (bbox) + pad
#define OUT_BBOX_OFF ((size_t)N_ROWS * SCORE_COLS)

typedef __attribute__((ext_vector_type(8))) short short8;
typedef __attribute__((ext_vector_type(8))) __bf16 bf16x8;
typedef __attribute__((ext_vector_type(4))) float floatx4;

// Active cls columns: IGNORE2 - 1, plus 79 (live col == detached col forward)
__device__ const int ACT[12] = {1,2,16,18,29,37,47,53,63,68,72,79};

// f32 -> bf16 (round-half-up), pack 2 into u32
__device__ inline unsigned pack2_bf16(float a, float b) {
  unsigned ua = __builtin_bit_cast(unsigned, a) + 0x8000u;
  unsigned ub = __builtin_bit_cast(unsigned, b) + 0x8000u;
  return (ua >> 16) | (ub & 0xFFFF0000u);
}
__device__ inline unsigned short to_bf16(float a) {
  return (unsigned short)((__builtin_bit_cast(unsigned, a) + 0x8000u) >> 16);
}

#define GLD16(g, l) __builtin_amdgcn_global_load_lds( \
    (const __attribute__((address_space(1))) void*)(g), \
    (__attribute__((address_space(3))) void*)(l), 16, 0, 0)

// ---- prep 1: pack W_cls / W_bbox / zero-pad into Wb (cols 1..12 by prep 2) --
__global__ __launch_bounds__(256) void prep_w_kernel(
    const float* __restrict__ W_cls, const float* __restrict__ b_cls,
    const float* __restrict__ W_bbox, const float* __restrict__ b_bbox,
    unsigned short* __restrict__ Wb, float* __restrict__ biasc)
{
  int c = blockIdx.x;          // GEMM column 0..383
  int t = threadIdx.x;
  if (c >= 1 && c <= 12) return;   // W_eff columns, written by prep_eff
  const float* src = nullptr;
  float bv = 0.f;
  if (c == 0)                  { src = W_cls;                        bv = b_cls[0]; }
  else if (c >= 13 && c < 337) { src = W_bbox + (size_t)(c-13)*DIM;  bv = b_bbox[c-13]; }
  unsigned u0 = 0, u1 = 0;
  if (src) {
    float4 v = *(const float4*)(src + t*4);
    u0 = pack2_bf16(v.x, v.y);
    u1 = pack2_bf16(v.z, v.w);
  }
  *(uint2*)(Wb + (size_t)c*DIM + t*4) = make_uint2(u0, u1);
  if (t == 0) biasc[c] = bv;
}

// ---- prep 2: W_eff[a][k] = sum_s sm[ACT[a]][s]/200 * W_sem[s][k] -----------
__global__ __launch_bounds__(1024) void prep_eff_kernel(
    const float* __restrict__ W_sem, const float* __restrict__ b_sem,
    const float* __restrict__ sm,
    unsigned short* __restrict__ Wb, float* __restrict__ biasc)
{
  __shared__ float red[256];
  const int a = blockIdx.x;        // 0..11
  const int k = threadIdx.x;       // 0..1023
  const float* smrow = sm + (size_t)ACT[a]*SDIM;
  float acc = 0.f;
#pragma unroll 4
  for (int s = 0; s < SDIM; ++s)
    acc += smrow[s] * W_sem[(size_t)s*DIM + k];
  Wb[(size_t)(1+a)*DIM + k] = to_bf16(acc * (1.0f/SDIM));

  if (k < 200) red[k] = smrow[k] * b_sem[k];
  else if (k < 256) red[k] = 0.f;
  __syncthreads();
  if (k == 0) {
    float b = 0.f;
    for (int s = 0; s < 256; ++s) b += red[s];
    biasc[1+a] = b * (1.0f/SDIM);
  }
}

// ---- GEMM: 64 rows x 192 cols per block, 4 waves at 64x48 ------------------
// Round-2's verified single-barrier double-buffered pipeline, reshaped for
// occupancy: acc[4][3] = 48 acc regs (total ~110 unified regs, <=128) ->
// 4 waves/SIMD; LDS 2x17.4KB -> 4 blocks/CU = 16 waves/CU in 4 INDEPENDENT
// barrier domains. When one block drains vmcnt at its barrier, three others
// issue MFMA (m114 inter-block overlap). Two col-blocks share each 64-row
// x-tile; adjacent blockIdx -> near-simultaneous -> second read L3-hit.
__global__ __launch_bounds__(256, 4) void gemm_kernel(
    const float* __restrict__ x, const unsigned short* __restrict__ Wb,
    const float* __restrict__ biasc, float* __restrict__ out)
{
  // per buffer: A 64 rows x (32 bf16 + 8 pad) = 5120 B; B 192 cols x 64 B
  __shared__ __align__(16) unsigned char lds[2 * 17408];

  const int t = threadIdx.x;
  const int rowbase = (blockIdx.x >> 1) << 6;
  const int colblk  = blockIdx.x & 1;       // 0: cols 0..191, 1: cols 192..383
  const int colbase = colblk * 192;

  const int lane = t & 63;
  const int quad = lane >> 4;
  const int l15 = lane & 15;
  const int w = t >> 6;               // wave 0..3, local cols [w*48, w*48+48)

  floatx4 acc[4][3] = {};

  const int arow = t >> 2;            // A staging: 8 f32 -> 16B bf16 per thread
  const int aseg = t & 3;
  const float* xa = x + (size_t)(rowbase + arow) * DIM + aseg * 8;
  const int awoff = arow * 80 + aseg * 16;

  const int bs = t & 3;               // B staging: 3 segs per thread
  const int bc = t >> 2;              // 0..63

  // B: global bf16 -> LDS direct; segment swizzle g = (s - (col>>1)) & 3
  // (col is LOCAL column; global row of Wb is colbase+col)
#define STAGE_B(buf, kt) do {                                         \
    unsigned char* Bsx = lds + (buf)*17408 + 5120;                    \
    _Pragma("unroll")                                                 \
    for (int i = 0; i < 3; ++i) {                                     \
      int col = i*64 + bc;                                            \
      int g = (bs - (col >> 1)) & 3;                                  \
      GLD16(Wb + (size_t)(colbase + col) * DIM + (kt)*32 + g*8,       \
            Bsx + i*4096 + w*1024);                                   \
    }                                                                 \
  } while (0)

  // ---- prologue: stage tile 0 into buf 0 (latency paid once) ----
  {
    float4 v0 = *(const float4*)(xa);
    float4 v1 = *(const float4*)(xa + 4);
    STAGE_B(0, 0);
    uint4 u;
    u.x = pack2_bf16(v0.x, v0.y);
    u.y = pack2_bf16(v0.z, v0.w);
    u.z = pack2_bf16(v1.x, v1.y);
    u.w = pack2_bf16(v1.z, v1.w);
    *(uint4*)(lds + awoff) = u;
  }
  __syncthreads();

#pragma unroll 2
  for (int kt = 0; kt < DIM/32; ++kt) {
    const int cur = kt & 1;
    unsigned char* As = lds + cur * 17408;
    unsigned char* Bs = As + 5120;

    // Issue next tile's loads FIRST (A into regs, B straight to LDS buf^1)
    float4 an0, an1;
    if (kt < DIM/32 - 1) {
      const float* p = xa + (kt + 1) * 32;
      an0 = *(const float4*)p;
      an1 = *(const float4*)(p + 4);
      STAGE_B(cur ^ 1, kt + 1);
    }

    // Compute current tile
    short8 a8[4], b8[3];
#pragma unroll
    for (int mi = 0; mi < 4; ++mi)
      a8[mi] = *(const short8*)(As + (mi*16 + l15) * 80 + quad * 16);
#pragma unroll
    for (int ni = 0; ni < 3; ++ni) {
      int col = w*48 + ni*16 + l15;
      int s2 = ((col >> 1) + quad) & 3;
      b8[ni] = *(const short8*)(Bs + col * 64 + s2 * 16);
    }
#pragma unroll
    for (int ni = 0; ni < 3; ++ni)
#pragma unroll
      for (int mi = 0; mi < 4; ++mi)
        acc[mi][ni] = __builtin_amdgcn_mfma_f32_16x16x32_bf16(
            __builtin_bit_cast(bf16x8, a8[mi]),
            __builtin_bit_cast(bf16x8, b8[ni]), acc[mi][ni], 0, 0, 0);

    // A pack + LDS write LAST: the dependent vmcnt wait on an0/an1 lands
    // here, hidden behind the ds_read+MFMA block above.
    if (kt < DIM/32 - 1) {
      uint4 u;
      u.x = pack2_bf16(an0.x, an0.y);
      u.y = pack2_bf16(an0.z, an0.w);
      u.z = pack2_bf16(an1.x, an1.y);
      u.w = pack2_bf16(an1.z, an1.w);
      *(uint4*)(lds + (cur ^ 1) * 17408 + awoff) = u;
    }
    __syncthreads();
  }

  // Epilogue: C/D layout col=lane&15, row=quad*4+reg
#pragma unroll
  for (int ni = 0; ni < 3; ++ni) {
    int c = colbase + w*48 + ni*16 + l15;
    if (c >= 337) continue;
    float bias = biasc[c];
    int outcol = (c == 0) ? 0 : (c <= 12 ? 1 + ACT[c-1] : c - 13);
#pragma unroll
    for (int mi = 0; mi < 4; ++mi) {
#pragma unroll
      for (int r = 0; r < 4; ++r) {
        int row = rowbase + mi*16 + quad*4 + r;
        float v = acc[mi][ni][r] + bias;
        if (c <= 12) out[(size_t)row * SCORE_COLS + outcol] = v;
        else         out[OUT_BBOX_OFF + (size_t)row * BBOX_COLS + outcol] = v;
      }
    }
  }

  // Zero-fill the 68 dead score columns for this block's 64 rows
  // (only the colblk==0 block of each row-tile does it)
  if (colblk == 0) {
    const unsigned long long MLO =
        (1ULL<<1)|(1ULL<<2)|(1ULL<<16)|(1ULL<<18)|(1ULL<<29)|(1ULL<<37)|
        (1ULL<<47)|(1ULL<<53)|(1ULL<<63);
    const unsigned MHI = (1u<<(68-64))|(1u<<(72-64))|(1u<<(79-64));
    for (int i = t; i < 64*80; i += 256) {
      int row = i / 80, col = i - row*80;
      bool act = (col < 64) ? ((MLO >> col) & 1ULL) : ((MHI >> (col-64)) & 1u);
      if (!act) out[(size_t)(rowbase+row) * SCORE_COLS + 1 + col] = 0.f;
    }
  }
}

// ---------------- launcher --------------------------------------------------
extern "C" void kernel_launch(void* const* d_in, const int* in_sizes, int n_in,
                              void* d_out, int out_size, void* d_ws, size_t ws_size,
                              hipStream_t stream) {
  const float* x      = (const float*)d_in[0];
  const float* W_cls  = (const float*)d_in[1];
  const float* b_cls  = (const float*)d_in[2];
  const float* W_sem  = (const float*)d_in[3];
  const float* b_sem  = (const float*)d_in[4];
  const float* W_bbox = (const float*)d_in[5];
  const float* b_bbox = (const float*)d_in[6];
  const float* smat   = (const float*)d_in[7];
  float* out = (float*)d_out;

  // ws layout: Wb bf16 [384*1024] = 786432 B; biasc [384] f32
  unsigned short* Wb = (unsigned short*)d_ws;
  float* biasc = (float*)((char*)d_ws + 786432);

  hipLaunchKernelGGL(prep_w_kernel, dim3(GEMM_COLS), dim3(256), 0, stream,
                     W_cls, b_cls, W_bbox, b_bbox, Wb, biasc);
  hipLaunchKernelGGL(prep_eff_kernel, dim3(12), dim3(1024), 0, stream,
                     W_sem, b_sem, smat, Wb, biasc);
  hipLaunchKernelGGL(gemm_kernel, dim3((N_ROWS/64) * 2), dim3(256), 0, stream,
                     x, Wb, biasc, out);
}

// Round 4
// 497.310 us; speedup vs baseline: 1.0210x; 1.0210x over previous
//
#include <hip/hip_runtime.h>
#include <hip/hip_bf16.h>
#include <stdint.h>

// Problem constants
#define N_ROWS 65536
#define DIM 1024
#define SDIM 200
#define SCORE_COLS 81
#define BBOX_COLS 324
#define GEMM_COLS 384      // 1 (cls) + 12 (folded sem->cls) + 324 (bbox) + pad
#define OUT_BBOX_OFF ((size_t)N_ROWS * SCORE_COLS)

typedef __attribute__((ext_vector_type(8))) short short8;
typedef __attribute__((ext_vector_type(8))) __bf16 bf16x8;
typedef __attribute__((ext_vector_type(4))) float floatx4;

// Active cls columns: IGNORE2 - 1, plus 79 (live col == detached col forward)
__device__ const int ACT[12] = {1,2,16,18,29,37,47,53,63,68,72,79};

// f32 -> bf16 (round-half-up), pack 2 into u32
__device__ inline unsigned pack2_bf16(float a, float b) {
  unsigned ua = __builtin_bit_cast(unsigned, a) + 0x8000u;
  unsigned ub = __builtin_bit_cast(unsigned, b) + 0x8000u;
  return (ua >> 16) | (ub & 0xFFFF0000u);
}
__device__ inline unsigned short to_bf16(float a) {
  return (unsigned short)((__builtin_bit_cast(unsigned, a) + 0x8000u) >> 16);
}

#define GLD16(g, l) __builtin_amdgcn_global_load_lds( \
    (const __attribute__((address_space(1))) void*)(g), \
    (__attribute__((address_space(3))) void*)(l), 16, 0, 0)

// ---- prep 1: pack W_cls / W_bbox / zero-pad into Wb (cols 1..12 by prep 2) --
__global__ __launch_bounds__(256) void prep_w_kernel(
    const float* __restrict__ W_cls, const float* __restrict__ b_cls,
    const float* __restrict__ W_bbox, const float* __restrict__ b_bbox,
    unsigned short* __restrict__ Wb, float* __restrict__ biasc)
{
  int c = blockIdx.x;          // GEMM column 0..383
  int t = threadIdx.x;
  if (c >= 1 && c <= 12) return;   // W_eff columns, written by prep_eff
  const float* src = nullptr;
  float bv = 0.f;
  if (c == 0)                  { src = W_cls;                        bv = b_cls[0]; }
  else if (c >= 13 && c < 337) { src = W_bbox + (size_t)(c-13)*DIM;  bv = b_bbox[c-13]; }
  unsigned u0 = 0, u1 = 0;
  if (src) {
    float4 v = *(const float4*)(src + t*4);
    u0 = pack2_bf16(v.x, v.y);
    u1 = pack2_bf16(v.z, v.w);
  }
  *(uint2*)(Wb + (size_t)c*DIM + t*4) = make_uint2(u0, u1);
  if (t == 0) biasc[c] = bv;
}

// ---- prep 2: W_eff[a][k] = sum_s sm[ACT[a]][s]/200 * W_sem[s][k] -----------
__global__ __launch_bounds__(1024) void prep_eff_kernel(
    const float* __restrict__ W_sem, const float* __restrict__ b_sem,
    const float* __restrict__ sm,
    unsigned short* __restrict__ Wb, float* __restrict__ biasc)
{
  __shared__ float red[256];
  const int a = blockIdx.x;        // 0..11
  const int k = threadIdx.x;       // 0..1023
  const float* smrow = sm + (size_t)ACT[a]*SDIM;
  float acc = 0.f;
#pragma unroll 4
  for (int s = 0; s < SDIM; ++s)
    acc += smrow[s] * W_sem[(size_t)s*DIM + k];
  Wb[(size_t)(1+a)*DIM + k] = to_bf16(acc * (1.0f/SDIM));

  if (k < 200) red[k] = smrow[k] * b_sem[k];
  else if (k < 256) red[k] = 0.f;
  __syncthreads();
  if (k == 0) {
    float b = 0.f;
    for (int s = 0; s < 256; ++s) b += red[s];
    biasc[1+a] = b * (1.0f/SDIM);
  }
}

// ---- GEMM: 64 rows x 384 cols per block, 4 waves at 64x96 ------------------
// Round-2 pipeline upgraded to COUNTED vmcnt (T4) + raw s_barrier:
//   per iter kt: issue [B(kt+1) 6xGLD16 -> Bbuf^1, A(kt+2) 2xload -> regs]
//   -> s_waitcnt vmcnt(10)  (oldest: B(kt) landed; newest 10 stay in flight)
//   -> s_barrier -> ds_read + 24 MFMA
//   -> s_waitcnt vmcnt(8)   (A(kt+1) regs valid)
//   -> pack A(kt+1) -> ds_write Abuf^1 -> lgkmcnt(0) -> s_barrier.
// No vmcnt(0) drain anywhere in the loop: the A HBM stream keeps ~16KB/block
// (~32KB/CU) continuously outstanding (Little's law fix for the 1.8 TB/s cap).
// Full 384-col blocks: x is read once (round-3 lesson: L3 does NOT absorb a
// second streaming pass over the 256MB x).
__global__ __launch_bounds__(256, 2) void gemm_kernel(
    const float* __restrict__ x, const unsigned short* __restrict__ Wb,
    const float* __restrict__ biasc, float* __restrict__ out)
{
  // per buffer: A 64 rows x (32 bf16 + 8 pad) = 5120 B; B 384 cols x 64 B
  __shared__ __align__(16) unsigned char lds[2 * 29696];

  const int t = threadIdx.x;
  const int rowbase = blockIdx.x << 6;

  const int lane = t & 63;
  const int quad = lane >> 4;
  const int l15 = lane & 15;
  const int w = t >> 6;               // wave 0..3, cols [w*96, w*96+96)

  floatx4 acc[4][6] = {};

  const int arow = t >> 2;            // A staging: 8 f32 -> 16B bf16 per thread
  const int aseg = t & 3;
  const float* xa = x + (size_t)(rowbase + arow) * DIM + aseg * 8;
  const int awoff = arow * 80 + aseg * 16;

  const int bs = t & 3;               // B staging: 6 segs per thread
  const int bc = t >> 2;

  // B: global bf16 -> LDS direct; segment swizzle g = (s - (col>>1)) & 3
#define STAGE_B(buf, kti) do {                                        \
    unsigned char* Bsx = lds + (buf)*29696 + 5120;                    \
    _Pragma("unroll")                                                 \
    for (int i = 0; i < 6; ++i) {                                     \
      int col = i*64 + bc;                                            \
      int g = (bs - (col >> 1)) & 3;                                  \
      GLD16(Wb + (size_t)col * DIM + (kti)*32 + g*8,                  \
            Bsx + i*4096 + w*1024);                                   \
    }                                                                 \
  } while (0)

#define PACK_WRITE(buf, v0, v1) do {                                  \
    uint4 u;                                                          \
    u.x = pack2_bf16((v0).x, (v0).y);                                 \
    u.y = pack2_bf16((v0).z, (v0).w);                                 \
    u.z = pack2_bf16((v1).x, (v1).y);                                 \
    u.w = pack2_bf16((v1).z, (v1).w);                                 \
    *(uint4*)(lds + (buf)*29696 + awoff) = u;                         \
  } while (0)

  // Two static A reg sets (depth-2 prefetch; static names per rule #20)
  float4 aA0, aA1, aB0, aB1;

  // ---- prologue: B(0)->buf0; A(0)->setA; A(1)->setB; pack A(0)->Abuf0 ----
  STAGE_B(0, 0);
  { const float* p = xa;      aA0 = *(const float4*)p; aA1 = *(const float4*)(p + 4); }
  { const float* p = xa + 32; aB0 = *(const float4*)p; aB1 = *(const float4*)(p + 4); }
  __builtin_amdgcn_sched_barrier(0);
  asm volatile("s_waitcnt vmcnt(2)" ::: "memory");   // B(0)+A(0) done; A(1) in flight
  __builtin_amdgcn_sched_barrier(0);
  PACK_WRITE(0, aA0, aA1);
  asm volatile("s_waitcnt lgkmcnt(0)" ::: "memory");
  __builtin_amdgcn_s_barrier();

  // ---- main loop: rolled x16, two static bodies (CUR = 0 / 1) ----
#define ITER(KT, CUR, LD0, LD1, PK0, PK1) do {                        \
    const int kb = ((KT)+1 < 32) ? (KT)+1 : 31;  /* B tile to stage */\
    const int ka = ((KT)+2 < 32) ? (KT)+2 : 31;  /* A tile to load  */\
    STAGE_B((CUR)^1, kb);                                             \
    { const float* p = xa + ka*32;                                    \
      LD0 = *(const float4*)p; LD1 = *(const float4*)(p + 4); }       \
    __builtin_amdgcn_sched_barrier(0);                                \
    asm volatile("s_waitcnt vmcnt(10)" ::: "memory");                 \
    __builtin_amdgcn_s_barrier();                                     \
    __builtin_amdgcn_sched_barrier(0);                                \
    {                                                                 \
      const unsigned char* As = lds + (CUR)*29696;                    \
      const unsigned char* Bs = As + 5120;                            \
      short8 a8[4], b8[6];                                            \
      _Pragma("unroll")                                               \
      for (int mi = 0; mi < 4; ++mi)                                  \
        a8[mi] = *(const short8*)(As + (mi*16 + l15) * 80 + quad * 16); \
      _Pragma("unroll")                                               \
      for (int ni = 0; ni < 6; ++ni) {                                \
        int col = w*96 + ni*16 + l15;                                 \
        int s2 = ((col >> 1) + quad) & 3;                             \
        b8[ni] = *(const short8*)(Bs + col * 64 + s2 * 16);           \
      }                                                               \
      _Pragma("unroll")                                               \
      for (int ni = 0; ni < 6; ++ni)                                  \
        _Pragma("unroll")                                             \
        for (int mi = 0; mi < 4; ++mi)                                \
          acc[mi][ni] = __builtin_amdgcn_mfma_f32_16x16x32_bf16(      \
              __builtin_bit_cast(bf16x8, a8[mi]),                     \
              __builtin_bit_cast(bf16x8, b8[ni]), acc[mi][ni], 0,0,0);\
    }                                                                 \
    __builtin_amdgcn_sched_barrier(0);                                \
    asm volatile("s_waitcnt vmcnt(8)" ::: "memory");                  \
    __builtin_amdgcn_sched_barrier(0);                                \
    PACK_WRITE((CUR)^1, PK0, PK1);                                    \
    asm volatile("s_waitcnt lgkmcnt(0)" ::: "memory");                \
    __builtin_amdgcn_s_barrier();                                     \
  } while (0)

#pragma unroll 1
  for (int kt = 0; kt < 32; kt += 2) {
    ITER(kt,     0, aA0, aA1, aB0, aB1);
    ITER(kt + 1, 1, aB0, aB1, aA0, aA1);
  }

  // Keep tail dummy loads live so vmcnt counts stay exact (rule #17)
  asm volatile("" :: "v"(aA0.x), "v"(aA1.x), "v"(aB0.x), "v"(aB1.x));

  // Epilogue: C/D layout col=lane&15, row=quad*4+reg
#pragma unroll
  for (int ni = 0; ni < 6; ++ni) {
    int c = w*96 + ni*16 + l15;
    if (c >= 337) continue;
    float bias = biasc[c];
    int outcol = (c == 0) ? 0 : (c <= 12 ? 1 + ACT[c-1] : c - 13);
#pragma unroll
    for (int mi = 0; mi < 4; ++mi) {
#pragma unroll
      for (int r = 0; r < 4; ++r) {
        int row = rowbase + mi*16 + quad*4 + r;
        float v = acc[mi][ni][r] + bias;
        if (c <= 12) out[(size_t)row * SCORE_COLS + outcol] = v;
        else         out[OUT_BBOX_OFF + (size_t)row * BBOX_COLS + outcol] = v;
      }
    }
  }

  // Zero-fill the 68 dead score columns for this block's 64 rows
  const unsigned long long MLO =
      (1ULL<<1)|(1ULL<<2)|(1ULL<<16)|(1ULL<<18)|(1ULL<<29)|(1ULL<<37)|
      (1ULL<<47)|(1ULL<<53)|(1ULL<<63);
  const unsigned MHI = (1u<<(68-64))|(1u<<(72-64))|(1u<<(79-64));
  for (int i = t; i < 64*80; i += 256) {
    int row = i / 80, col = i - row*80;
    bool act = (col < 64) ? ((MLO >> col) & 1ULL) : ((MHI >> (col-64)) & 1u);
    if (!act) out[(size_t)(rowbase+row) * SCORE_COLS + 1 + col] = 0.f;
  }
}

// ---------------- launcher --------------------------------------------------
extern "C" void kernel_launch(void* const* d_in, const int* in_sizes, int n_in,
                              void* d_out, int out_size, void* d_ws, size_t ws_size,
                              hipStream_t stream) {
  const float* x      = (const float*)d_in[0];
  const float* W_cls  = (const float*)d_in[1];
  const float* b_cls  = (const float*)d_in[2];
  const float* W_sem  = (const float*)d_in[3];
  const float* b_sem  = (const float*)d_in[4];
  const float* W_bbox = (const float*)d_in[5];
  const float* b_bbox = (const float*)d_in[6];
  const float* smat   = (const float*)d_in[7];
  float* out = (float*)d_out;

  // ws layout: Wb bf16 [384*1024] = 786432 B; biasc [384] f32
  unsigned short* Wb = (unsigned short*)d_ws;
  float* biasc = (float*)((char*)d_ws + 786432);

  hipLaunchKernelGGL(prep_w_kernel, dim3(GEMM_COLS), dim3(256), 0, stream,
                     W_cls, b_cls, W_bbox, b_bbox, Wb, biasc);
  hipLaunchKernelGGL(prep_eff_kernel, dim3(12), dim3(1024), 0, stream,
                     W_sem, b_sem, smat, Wb, biasc);
  hipLaunchKernelGGL(gemm_kernel, dim3(N_ROWS/64), dim3(256), 0, stream,
                     x, Wb, biasc, out);
}

// Round 5
// 483.407 us; speedup vs baseline: 1.0504x; 1.0288x over previous
//
#include <hip/hip_runtime.h>
#include <hip/hip_bf16.h>
#include <stdint.h>

// Problem constants
#define N_ROWS 65536
#define DIM 1024
#define SDIM 200
#define SCORE_COLS 81
#define BBOX_COLS 324
#define GEMM_COLS 384      // 1 (cls) + 12 (folded sem->cls) + 324 (bbox) + pad
#define OUT_BBOX_OFF ((size_t)N_ROWS * SCORE_COLS)
#define KT_BYTES 24576     // one kt's B LDS image: 384 cols x 64 B

typedef __attribute__((ext_vector_type(8))) short short8;
typedef __attribute__((ext_vector_type(8))) __bf16 bf16x8;
typedef __attribute__((ext_vector_type(4))) float floatx4;

// Active cls columns: IGNORE2 - 1, plus 79 (live col == detached col forward)
__device__ const int ACT[12] = {1,2,16,18,29,37,47,53,63,68,72,79};

// f32 -> bf16 (round-half-up), pack 2 into u32
__device__ inline unsigned pack2_bf16(float a, float b) {
  unsigned ua = __builtin_bit_cast(unsigned, a) + 0x8000u;
  unsigned ub = __builtin_bit_cast(unsigned, b) + 0x8000u;
  return (ua >> 16) | (ub & 0xFFFF0000u);
}
__device__ inline unsigned short to_bf16(float a) {
  return (unsigned short)((__builtin_bit_cast(unsigned, a) + 0x8000u) >> 16);
}

#define GLD16(g, l) __builtin_amdgcn_global_load_lds( \
    (const __attribute__((address_space(1))) void*)(g), \
    (__attribute__((address_space(3))) void*)(l), 16, 0, 0)

// Wb2 layout: per kt (32 of them), the exact 24576-B LDS image staging copies:
//   image[kt][i*4096 + tthr*16] (tthr = 0..255) holds Wb_row(col)[kt*32 + g*8 .. +8)
//   with col = i*64 + (tthr>>2), seg swizzle s = tthr&3 = (g + (col>>1)) & 3.
// Staging then reads CONTIGUOUS 1 KB per wave-instruction (round-4 lesson:
// the old [col][k] layout cost 16 scattered 64-B lines per GLD16 -> TA-bound).

// ---- prep 1: W_cls / W_bbox / zero-pad -> Wb2 image (cols 1..12 by prep 2) --
__global__ __launch_bounds__(128) void prep_w_kernel(
    const float* __restrict__ W_cls, const float* __restrict__ b_cls,
    const float* __restrict__ W_bbox, const float* __restrict__ b_bbox,
    unsigned char* __restrict__ Wb2, float* __restrict__ biasc)
{
  int c = blockIdx.x;          // GEMM column 0..383
  int t = threadIdx.x;         // 0..127, 8 k-elems each
  if (c >= 1 && c <= 12) return;   // W_eff columns, written by prep_eff
  const float* src = nullptr;
  float bv = 0.f;
  if (c == 0)                  { src = W_cls;                        bv = b_cls[0]; }
  else if (c >= 13 && c < 337) { src = W_bbox + (size_t)(c-13)*DIM;  bv = b_bbox[c-13]; }
  uint4 u = make_uint4(0u, 0u, 0u, 0u);
  if (src) {
    float4 v0 = *(const float4*)(src + t*8);
    float4 v1 = *(const float4*)(src + t*8 + 4);
    u.x = pack2_bf16(v0.x, v0.y);
    u.y = pack2_bf16(v0.z, v0.w);
    u.z = pack2_bf16(v1.x, v1.y);
    u.w = pack2_bf16(v1.z, v1.w);
  }
  int kt = t >> 2, g = t & 3;               // k = kt*32 + g*8
  int i = c >> 6, bc = c & 63;
  int s = (g + (c >> 1)) & 3;               // baked segment swizzle
  int tthr = bc*4 + s;
  *(uint4*)(Wb2 + (size_t)kt*KT_BYTES + i*4096 + tthr*16) = u;
  if (t == 0) biasc[c] = bv;
}

// ---- prep 2: W_eff[a][k] = sum_s sm[ACT[a]][s]/200 * W_sem[s][k] -----------
__global__ __launch_bounds__(1024) void prep_eff_kernel(
    const float* __restrict__ W_sem, const float* __restrict__ b_sem,
    const float* __restrict__ sm,
    unsigned char* __restrict__ Wb2, float* __restrict__ biasc)
{
  __shared__ float red[256];
  const int a = blockIdx.x;        // 0..11
  const int k = threadIdx.x;       // 0..1023
  const float* smrow = sm + (size_t)ACT[a]*SDIM;
  float acc = 0.f;
#pragma unroll 4
  for (int s = 0; s < SDIM; ++s)
    acc += smrow[s] * W_sem[(size_t)s*DIM + k];
  {
    const int c = 1 + a;                   // GEMM column (i = 0, bc = c)
    int kt = k >> 5, kk = k & 31, g = kk >> 3, e = kk & 7;
    int s2 = (g + (c >> 1)) & 3;
    int tthr = c*4 + s2;
    *(unsigned short*)(Wb2 + (size_t)kt*KT_BYTES + tthr*16 + e*2) =
        to_bf16(acc * (1.0f/SDIM));
  }

  if (k < 200) red[k] = smrow[k] * b_sem[k];
  else if (k < 256) red[k] = 0.f;
  __syncthreads();
  if (k == 0) {
    float b = 0.f;
    for (int s = 0; s < 256; ++s) b += red[s];
    biasc[1+a] = b * (1.0f/SDIM);
  }
}

// ---- GEMM: 64 rows x 384 cols per block, 4 waves at 64x96 ------------------
// Round-2's verified single-barrier double-buffered pipeline, with B staging
// reading the pre-tiled Wb2 image: 6 GLD16/thread, each wave-instruction a
// contiguous 1 KB burst (was 16 scattered 64-B lines). Compute phase, A path,
// LDS layout and numerics are byte-identical to round 2.
__global__ __launch_bounds__(256, 2) void gemm_kernel(
    const float* __restrict__ x, const unsigned char* __restrict__ Wb2,
    const float* __restrict__ biasc, float* __restrict__ out)
{
  // per buffer: A 64 rows x (32 bf16 + 8 pad) = 5120 B; B image 24576 B
  __shared__ __align__(16) unsigned char lds[2 * 29696];

  const int t = threadIdx.x;
  const int rowbase = blockIdx.x << 6;

  const int lane = t & 63;
  const int quad = lane >> 4;
  const int l15 = lane & 15;
  const int w = t >> 6;               // wave 0..3, cols [w*96, w*96+96)

  floatx4 acc[4][6] = {};

  const int arow = t >> 2;            // A staging: 8 f32 -> 16B bf16 per thread
  const int aseg = t & 3;
  const float* xa = x + (size_t)(rowbase + arow) * DIM + aseg * 8;
  const int awoff = arow * 80 + aseg * 16;

  // B: contiguous image copy, 6 x 1KB bursts per wave
#define STAGE_B(buf, kti) do {                                        \
    unsigned char* Bsx = lds + (buf)*29696 + 5120;                    \
    const unsigned char* gsrc = Wb2 + (size_t)(kti)*KT_BYTES + t*16;  \
    _Pragma("unroll")                                                 \
    for (int i = 0; i < 6; ++i)                                       \
      GLD16(gsrc + i*4096, Bsx + i*4096 + w*1024);                    \
  } while (0)

  // ---- prologue: stage tile 0 into buf 0 (latency paid once) ----
  {
    float4 v0 = *(const float4*)(xa);
    float4 v1 = *(const float4*)(xa + 4);
    STAGE_B(0, 0);
    uint4 u;
    u.x = pack2_bf16(v0.x, v0.y);
    u.y = pack2_bf16(v0.z, v0.w);
    u.z = pack2_bf16(v1.x, v1.y);
    u.w = pack2_bf16(v1.z, v1.w);
    *(uint4*)(lds + awoff) = u;
  }
  __syncthreads();

#pragma unroll 2
  for (int kt = 0; kt < DIM/32; ++kt) {
    const int cur = kt & 1;
    unsigned char* As = lds + cur * 29696;
    unsigned char* Bs = As + 5120;

    // Issue next tile's loads FIRST (A into regs, B straight to LDS buf^1)
    float4 an0, an1;
    if (kt < DIM/32 - 1) {
      const float* p = xa + (kt + 1) * 32;
      an0 = *(const float4*)p;
      an1 = *(const float4*)(p + 4);
      STAGE_B(cur ^ 1, kt + 1);
    }

    // Compute current tile
    short8 a8[4], b8[6];
#pragma unroll
    for (int mi = 0; mi < 4; ++mi)
      a8[mi] = *(const short8*)(As + (mi*16 + l15) * 80 + quad * 16);
#pragma unroll
    for (int ni = 0; ni < 6; ++ni) {
      int col = w*96 + ni*16 + l15;
      int s2 = ((col >> 1) + quad) & 3;
      b8[ni] = *(const short8*)(Bs + col * 64 + s2 * 16);
    }
#pragma unroll
    for (int ni = 0; ni < 6; ++ni)
#pragma unroll
      for (int mi = 0; mi < 4; ++mi)
        acc[mi][ni] = __builtin_amdgcn_mfma_f32_16x16x32_bf16(
            __builtin_bit_cast(bf16x8, a8[mi]),
            __builtin_bit_cast(bf16x8, b8[ni]), acc[mi][ni], 0, 0, 0);

    // A pack + LDS write LAST: the dependent vmcnt wait on an0/an1 lands
    // here, hidden behind the ds_read+MFMA block above.
    if (kt < DIM/32 - 1) {
      uint4 u;
      u.x = pack2_bf16(an0.x, an0.y);
      u.y = pack2_bf16(an0.z, an0.w);
      u.z = pack2_bf16(an1.x, an1.y);
      u.w = pack2_bf16(an1.z, an1.w);
      *(uint4*)(lds + (cur ^ 1) * 29696 + awoff) = u;
    }
    __syncthreads();
  }

  // Epilogue: C/D layout col=lane&15, row=quad*4+reg
#pragma unroll
  for (int ni = 0; ni < 6; ++ni) {
    int c = w*96 + ni*16 + l15;
    if (c >= 337) continue;
    float bias = biasc[c];
    int outcol = (c == 0) ? 0 : (c <= 12 ? 1 + ACT[c-1] : c - 13);
#pragma unroll
    for (int mi = 0; mi < 4; ++mi) {
#pragma unroll
      for (int r = 0; r < 4; ++r) {
        int row = rowbase + mi*16 + quad*4 + r;
        float v = acc[mi][ni][r] + bias;
        if (c <= 12) out[(size_t)row * SCORE_COLS + outcol] = v;
        else         out[OUT_BBOX_OFF + (size_t)row * BBOX_COLS + outcol] = v;
      }
    }
  }

  // Zero-fill the 68 dead score columns for this block's 64 rows
  const unsigned long long MLO =
      (1ULL<<1)|(1ULL<<2)|(1ULL<<16)|(1ULL<<18)|(1ULL<<29)|(1ULL<<37)|
      (1ULL<<47)|(1ULL<<53)|(1ULL<<63);
  const unsigned MHI = (1u<<(68-64))|(1u<<(72-64))|(1u<<(79-64));
  for (int i = t; i < 64*80; i += 256) {
    int row = i / 80, col = i - row*80;
    bool act = (col < 64) ? ((MLO >> col) & 1ULL) : ((MHI >> (col-64)) & 1u);
    if (!act) out[(size_t)(rowbase+row) * SCORE_COLS + 1 + col] = 0.f;
  }
}

// ---------------- launcher --------------------------------------------------
extern "C" void kernel_launch(void* const* d_in, const int* in_sizes, int n_in,
                              void* d_out, int out_size, void* d_ws, size_t ws_size,
                              hipStream_t stream) {
  const float* x      = (const float*)d_in[0];
  const float* W_cls  = (const float*)d_in[1];
  const float* b_cls  = (const float*)d_in[2];
  const float* W_sem  = (const float*)d_in[3];
  const float* b_sem  = (const float*)d_in[4];
  const float* W_bbox = (const float*)d_in[5];
  const float* b_bbox = (const float*)d_in[6];
  const float* smat   = (const float*)d_in[7];
  float* out = (float*)d_out;

  // ws layout: Wb2 image [32*24576] = 786432 B; biasc [384] f32
  unsigned char* Wb2 = (unsigned char*)d_ws;
  float* biasc = (float*)((char*)d_ws + 786432);

  hipLaunchKernelGGL(prep_w_kernel, dim3(GEMM_COLS), dim3(128), 0, stream,
                     W_cls, b_cls, W_bbox, b_bbox, Wb2, biasc);
  hipLaunchKernelGGL(prep_eff_kernel, dim3(12), dim3(1024), 0, stream,
                     W_sem, b_sem, smat, Wb2, biasc);
  hipLaunchKernelGGL(gemm_kernel, dim3(N_ROWS/64), dim3(256), 0, stream,
                     x, Wb2, biasc, out);
}